// Round 2
// 134.583 us; speedup vs baseline: 1.0053x; 1.0053x over previous
//
#include <hip/hip_runtime.h>
#include <math.h>

#define T_FRAMES 65536
#define FSTRIDE  345          // 115 points * 3 coords (float32 elements)
#define ROWB     4784         // bytes per output row (1196 floats)

// ---------------------------------------------------------------------------
// Workspace-free variant: ALL inter-kernel state is staged inside d_out and
// later overwritten by phase3 (phase3 writes every byte of every row).
//
// scratch layout inside OUT buffer:
//   [0, 16384)      ushort keepbits[8192]   2 bits per frame: {left, right} keep
//   [16384, 32768)  int2   partials[2048]   per-block {cl, cr} nonzero counts
//   row r bytes [r*4784, r*4784+16): int4 record {cond, order[r], order[r+1], 0}
//
// Safety argument:
//  - phase2 (single block) reads ALL scratch into regs/LDS before writing any
//    record, so record-over-scratch overlap is ordered by its own barriers.
//  - phase3 block r reads only its own row's 16-B record before overwriting
//    the row -> no cross-block hazard.
//  - every scratch byte is rewritten each launch -> graph-replay determinism.
// ---------------------------------------------------------------------------

// invert triu(k=1) linear index l -> (a,b) for an N-point set; <=N iterations
__device__ __forceinline__ void triu_ab(int l, int N, int& a, int& b) {
  int a0 = 0, rem = l, row = N - 1;
  while (rem >= row) { rem -= row; ++a0; --row; }
  a = a0; b = a0 + 1 + rem;
}

// ---- phase 1: per-frame keep bits (packed) + per-block count partials ------
// 2048 blocks x 256 threads; each wave handles 8 consecutive frames.
// Per-frame sum reduction uses the SAME 63-lane/6-round shfl butterfly as the
// previously-passing kernel -> bit-identical keep decisions.
__global__ __launch_bounds__(256) void phase1(const float* __restrict__ x,
                                              ushort* __restrict__ keepbits,
                                              int2* __restrict__ partials) {
  const int wave = threadIdx.x >> 6;
  const int lane = threadIdx.x & 63;
  const int w = (blockIdx.x << 2) + wave;        // global wave id, 8192 total
  const float* xw = x + (size_t)w * 8 * FSTRIDE;

  int cl = 0, cr = 0;                            // nonzero counts, accumulated
  unsigned bits = 0;
  for (int i = 0; i < 8; ++i) {
    const float* xf = xw + i * FSTRIDE;
    float a = 0.f, b = 0.f;
    if (lane < 63) {
      a = xf[120 + lane]; if (isnan(a)) a = 0.f;  // left hand: pts 40..60
      b = xf[282 + lane]; if (isnan(b)) b = 0.f;  // right hand: pts 94..114
    }
    cl += (a != 0.f);
    cr += (b != 0.f);
    float va = a, vb = b;
    for (int off = 32; off > 0; off >>= 1) {
      va += __shfl_down(va, off, 64);
      vb += __shfl_down(vb, off, 64);
    }
    if (lane == 0)
      bits |= (((va != 0.f) ? 1u : 0u) << (2 * i)) |
              (((vb != 0.f) ? 1u : 0u) << (2 * i + 1));
  }
  for (int off = 32; off > 0; off >>= 1) {
    cl += __shfl_down(cl, off, 64);
    cr += __shfl_down(cr, off, 64);
  }
  __shared__ int bL[4], bR[4];
  if (lane == 0) {
    keepbits[w] = (ushort)bits;
    bL[wave] = cl; bR[wave] = cr;
  }
  __syncthreads();
  if (threadIdx.x == 0)
    partials[blockIdx.x] = make_int2(bL[0] + bL[1] + bL[2] + bL[3],
                                     bR[0] + bR[1] + bR[2] + bR[3]);
}

// ---- phase 2: cond + first 101 entries of the stable keep-first order ------
// Single block, 1024 threads. Flags live in 16 KB of LDS; ballot/popcount
// compaction identical in structure to the previously-passing kernel.
// Writes per-row records (replicated) so phase3 has no cross-block reads.
__global__ __launch_bounds__(1024) void phase2(const uint4* __restrict__ kb,   // keepbits as uint4[1024]
                                               const int4* __restrict__ pp,   // partials as int4[1024]
                                               char* __restrict__ outB) {
  const int tid  = threadIdx.x;
  const int lane = tid & 63;
  const int wave = tid >> 6;
  __shared__ unsigned int sKeep[4096];     // 16 KB: 2 bits/frame
  __shared__ int sL[16], sR[16];
  __shared__ unsigned long long sM[16];
  __shared__ int sOrder[104];
  __shared__ int sBase, sCond;

  // stage keep bits into LDS (all scratch reads happen before any record write)
  uint4 v = kb[tid];
  sKeep[tid * 4 + 0] = v.x; sKeep[tid * 4 + 1] = v.y;
  sKeep[tid * 4 + 2] = v.z; sKeep[tid * 4 + 3] = v.w;

  // totals from per-block partials: int4 covers two blocks' {cl,cr}
  int4 p = pp[tid];
  int cl = p.x + p.z, cr = p.y + p.w;
  for (int off = 32; off > 0; off >>= 1) {
    cl += __shfl_down(cl, off, 64);
    cr += __shfl_down(cr, off, 64);
  }
  if (lane == 0) { sL[wave] = cl; sR[wave] = cr; }
  __syncthreads();
  if (tid == 0) {
    int L = 0, R = 0;
    for (int i = 0; i < 16; ++i) { L += sL[i]; R += sR[i]; }
    sCond = (L > R) ? 1 : 0;
    sBase = 0;
  }
  __syncthreads();
  const int cond = sCond;
  const int sel  = cond ? 0 : 1;           // bit 2i = left keep, 2i+1 = right

  // stable partition: keep-first (pass 0), then non-keep (pass 1)
  for (int pass = 0; pass < 2; ++pass) {
    for (int base = 0; base < T_FRAMES; base += 1024) {
      if (sBase >= 101) break;             // uniform; sBase stable since barrier
      const int f = base + tid;
      const unsigned u = sKeep[f >> 4];
      int flag = (int)((u >> (((f >> 3) & 1) * 16 + (f & 7) * 2 + sel)) & 1u);
      if (pass) flag ^= 1;
      unsigned long long m = __ballot(flag);
      if (lane == 0) sM[wave] = m;
      __syncthreads();
      int pos = sBase;
      for (int w2 = 0; w2 < wave; ++w2) pos += (int)__popcll(sM[w2]);
      pos += (int)__popcll(m & ((1ull << lane) - 1ull));
      if (flag && pos < 101) sOrder[pos] = f;
      __syncthreads();
      if (tid == 0) {
        int tot = 0;
        for (int w2 = 0; w2 < 16; ++w2) tot += (int)__popcll(sM[w2]);
        sBase += tot;
      }
      __syncthreads();
    }
  }
  __syncthreads();
  // replicate {cond, f, g} into each output row's first 16 bytes
  if (tid < 100) {
    int4 rec;
    rec.x = cond; rec.y = sOrder[tid]; rec.z = sOrder[tid + 1]; rec.w = 0;
    *(int4*)(outB + (size_t)tid * ROWB) = rec;
  }
}

// ---- phase 3: build the 100 x 1196 output ----------------------------------
__global__ __launch_bounds__(256) void phase3(const float* __restrict__ x,
                                              float* __restrict__ out) {
  __shared__ float A[258], B[258];   // xfeat (86 pts x 3) for frames f, g
  const int row = blockIdx.x;
  float* o = out + (size_t)row * 1196;
  // read this row's record BEFORE any write to the row (per-thread broadcast load)
  const int4 rec = *(const int4*)o;
  const int cond = rec.x;
  const int f = rec.y, g = rec.z;
  const float* xf = x + (size_t)f * FSTRIDE;
  const float* xg = x + (size_t)g * FSTRIDE;

  for (int idx = threadIdx.x; idx < 258; idx += blockDim.x) {
    const int p = idx / 3, c = idx - p * 3;
    // xfeat point -> source point in x: hand(21) | pose(25) | lip(40)
    const int s = (p < 21) ? (cond ? 40 + p : 94 + p) : ((p < 46) ? p + 40 : p - 46);
    float va = xf[s * 3 + c]; if (isnan(va)) va = 0.f;
    float vb = xg[s * 3 + c]; if (isnan(vb)) vb = 0.f;
    if (cond && c == 0) { va = -va; vb = -vb; }   // xc negation on all 86 points
    A[idx] = va; B[idx] = vb;
  }
  __syncthreads();

  for (int j = threadIdx.x; j < 1196; j += blockDim.x) {
    float v;
    if (j < 306) {                       // positional: xfeat (153) then dxyz (153)
      int jj = j; bool diff = false;
      if (jj >= 153) { diff = true; jj -= 153; }
      int p, c;
      if (jj < 63)       { p = jj / 3;             c = jj - p * 3; }
      else if (jj < 113) { int t = jj - 63;  p = 21 + (t >> 1); c = t & 1; }
      else               { int t = jj - 113; p = 46 + (t >> 1); c = t & 1; }
      v = A[p * 3 + c];
      if (diff) v -= B[p * 3 + c];
    } else if (j < 516) {                // hdist: 21 pts, 3D, 210 pairs
      int a, b; triu_ab(j - 306, 21, a, b);
      const float dx = A[a*3]   - A[b*3];
      const float dy = A[a*3+1] - A[b*3+1];
      const float dz = A[a*3+2] - A[b*3+2];
      v = sqrtf(dx*dx + dy*dy + dz*dz);
    } else if (j < 816) {                // pdist: pose 25 pts, 2D, 300 pairs
      int a, b; triu_ab(j - 516, 25, a, b);
      a += 21; b += 21;
      const float dx = A[a*3] - A[b*3], dy = A[a*3+1] - A[b*3+1];
      v = sqrtf(dx*dx + dy*dy);
    } else if (j < 1006) {               // oldist: lip pts 46..65, 2D, 190 pairs
      int a, b; triu_ab(j - 816, 20, a, b);
      a += 46; b += 46;
      const float dx = A[a*3] - A[b*3], dy = A[a*3+1] - A[b*3+1];
      v = sqrtf(dx*dx + dy*dy);
    } else {                             // ildist: lip pts 66..85, 2D, 190 pairs
      int a, b; triu_ab(j - 1006, 20, a, b);
      a += 66; b += 66;
      const float dx = A[a*3] - A[b*3], dy = A[a*3+1] - A[b*3+1];
      v = sqrtf(dx*dx + dy*dy);
    }
    o[j] = v;
  }
}

extern "C" void kernel_launch(void* const* d_in, const int* in_sizes, int n_in,
                              void* d_out, int out_size, void* d_ws, size_t ws_size,
                              hipStream_t stream) {
  (void)in_sizes; (void)n_in; (void)out_size; (void)d_ws; (void)ws_size;
  const float* x = (const float*)d_in[0];
  char* ob = (char*)d_out;
  ushort* keepbits = (ushort*)ob;            // [0, 16384)
  int2*   partials = (int2*)(ob + 16384);    // [16384, 32768)

  phase1<<<2048, 256, 0, stream>>>(x, keepbits, partials);
  phase2<<<1, 1024, 0, stream>>>((const uint4*)ob, (const int4*)(ob + 16384), ob);
  phase3<<<100, 256, 0, stream>>>(x, (float*)d_out);
}